// Round 7
// baseline (159.947 us; speedup 1.0000x reference)
//
#include <hip/hip_runtime.h>
#include <hip/hip_bf16.h>

// Head attention, B=8, T=4096, C=512, h=64, prefix-causal mask (j <= max(i,1023)).
// Inputs/output fp32; internal q/Kf/Vf bf16 in ws. Round-7: attn split to 1024
// blocks x 32 q-rows (4 blocks/CU -> 16 waves/CU TLP), LDS overlay, sbb-serial
// S processing, kA loads in sp-loop, q pre-scaled by C^-0.5*log2e in proj so
// attn applies exp2 directly. proj/wtrans otherwise unchanged from round 6.

typedef short short8 __attribute__((ext_vector_type(8)));   // 8 bf16 = 4 VGPRs
typedef float floatx4 __attribute__((ext_vector_type(4)));

// fp32 -> bf16 RNE (scalar)
static __device__ __forceinline__ unsigned short f2b(float f) {
  unsigned u = __float_as_uint(f);
  unsigned r = (u + 0x7fffu + ((u >> 16) & 1u)) >> 16;
  return (unsigned short)r;
}

// pack 2 fp32 -> bf16x2 dword (RNE packed convert)
static __device__ __forceinline__ unsigned pkbf(float lo, float hi) {
  __hip_bfloat162 t = __float22bfloat162_rn(make_float2(lo, hi));
  unsigned d;
  __builtin_memcpy(&d, &t, 4);
  return d;
}

union S8U {
  short8 s;
  unsigned u[4];
};

// ---------------------------------------------------------------------------
// Kernel 0: weights -> frag-linear Wtf[(ks*12 + j)*512 + lane*8 + e] bf16.
// j = 0..11: matrix m = j>>2 (q,k,v), n-tile jj = j&3. Value = W[k][n] with
// n = jj*16 + (lane&15), k = ks*32 + (lane>>4)*8 + e.
__global__ __launch_bounds__(256) void wtrans(
    const float* __restrict__ Wq, const float* __restrict__ Wk,
    const float* __restrict__ Wv, unsigned short* __restrict__ Wtf) {
  int o = blockIdx.x * 256 + threadIdx.x;  // 0..98303
  int e = o & 7;
  int ln = (o >> 3) & 63;
  int jg = o >> 9;          // ks*12 + j, 0..191
  int ks = jg / 12;
  int j = jg % 12;
  int m = j >> 2;
  int n = (j & 3) * 16 + (ln & 15);
  int k = ks * 32 + (ln >> 4) * 8 + e;
  const float* W = (m == 0) ? Wq : (m == 1) ? Wk : Wv;
  Wtf[o] = f2b(W[k * 64 + n]);
}

// ---------------------------------------------------------------------------
// Kernel 1: 1024 blocks x 32 rows. Wave pair pr = w>>1 owns rows g0+pr*16..+15;
// parity p = w&1 takes ks = p, p+2, ... (8 iters). No barriers / no LDS in the
// main loop. One LDS combine, then direct register->global epilogue stores
// (q row-major PRE-SCALED by C^-0.5*log2e, Kf/Vf frag-linear).
__global__ __launch_bounds__(256, 3) void proj(
    const float* __restrict__ x, const unsigned short* __restrict__ Wtf,
    unsigned short* __restrict__ q, unsigned short* __restrict__ Kf,
    unsigned short* __restrict__ Vf) {
  __shared__ float Cc[2][12][16][17];  // partial-acc exchange, padded

  const int tid = threadIdx.x;
  const int lane = tid & 63;
  const int w = tid >> 6;
  const int u = lane & 15;
  const int qd = lane >> 4;
  const int pr = w >> 1;   // row-pair: rows g0 + pr*16 .. +15
  const int p = w & 1;     // ks parity
  const int g0 = blockIdx.x * 32;

  floatx4 acc[12];
#pragma unroll
  for (int j = 0; j < 12; ++j) acc[j] = (floatx4)0.0f;

  const float* xr = x + (size_t)(g0 + pr * 16 + u) * 512;

  for (int it = 0; it < 8; ++it) {
    const int ks = p + it * 2;
    floatx4 x0 = *reinterpret_cast<const floatx4*>(&xr[ks * 32 + qd * 8]);
    floatx4 x1 = *reinterpret_cast<const floatx4*>(&xr[ks * 32 + qd * 8 + 4]);
    S8U a;
    a.u[0] = pkbf(x0[0], x0[1]);
    a.u[1] = pkbf(x0[2], x0[3]);
    a.u[2] = pkbf(x1[0], x1[1]);
    a.u[3] = pkbf(x1[2], x1[3]);
#pragma unroll
    for (int j = 0; j < 12; ++j) {
      short8 bfr = *reinterpret_cast<const short8*>(&Wtf[(size_t)(ks * 12 + j) * 512 + lane * 8]);
      acc[j] = __builtin_amdgcn_mfma_f32_16x16x32_bf16(a.s, bfr, acc[j], 0, 0, 0);
    }
  }

  // combine parities: p==1 publishes, p==0 adds
  if (p == 1) {
#pragma unroll
    for (int j = 0; j < 12; ++j)
#pragma unroll
      for (int r = 0; r < 4; ++r)
        Cc[pr][j][qd * 4 + r][u] = acc[j][r];
  }
  __syncthreads();
  if (p == 0) {
#pragma unroll
    for (int j = 0; j < 12; ++j)
#pragma unroll
      for (int r = 0; r < 4; ++r)
        acc[j][r] += Cc[pr][j][qd * 4 + r][u];

    // ---- epilogue (2 active waves, 16 rows each) ----
    const float cexp = 0.04419417382415922f * 1.4426950408889634f;  // C^-0.5*log2e
    const int rbase = g0 + pr * 16;
    const int b = rbase >> 12;
    const int t = rbase & 4095;
    const int kt = t >> 6;
    const int sb = ((blockIdx.x & 1) << 1) + pr;      // K frag row-block in tile
    const int sp = blockIdx.x & 1;                     // V frag s-half in tile
    unsigned short* kfb = Kf + ((size_t)(b * 64 + kt)) * 4096;
    unsigned short* vfb = Vf + ((size_t)(b * 64 + kt)) * 4096;

#pragma unroll
    for (int j = 0; j < 4; ++j)
#pragma unroll
      for (int r = 0; r < 4; ++r) {
        // q row-major, pre-scaled into exp2 domain
        q[(size_t)(rbase + qd * 4 + r) * 64 + j * 16 + u] = f2b(acc[j][r] * cexp);
        // Kf: frag f = kh*4+sb; lane (qd_f, u_f=qd*4+r), elem e=u&7
        {
          int kh = j >> 1;
          int qd_f = ((j & 1) << 1) + (u >> 3);
          kfb[(size_t)(kh * 4 + sb) * 512 + (qd_f * 16 + (qd * 4 + r)) * 8 + (u & 7)] =
              f2b(acc[4 + j][r]);
        }
        // Vf: frag f = sp*4+mb (mb=j); lane (qd_f, u_f=u), elem e
        {
          int qd_f = pr * 2 + (qd >> 1);
          int e = ((qd & 1) << 2) + r;
          vfb[(size_t)(sp * 4 + j) * 512 + (qd_f * 16 + u) * 8 + e] = f2b(acc[8 + j][r]);
        }
      }
  }
}

// ---------------------------------------------------------------------------
// Kernel 2: flash attention, transposed-S, 32 q-rows per block. 1024 blocks:
// quad m = bx>>2 (b = m>>5, u0 = m&31), slot s4 = bx&3 -> qt = (s4&1)? 63-u0
// : u0, rh = s4>>1 (co-resident quads get heavy+light qt of one batch).
// 4 waves each own all 32 rows for kt = w, w+4, ... S^T = K Q^T (q pre-scaled
// -> exp2 direct); P^T packed to B-frags via wave-private LDS; O^T = V^T P^T.
__global__ __launch_bounds__(256, 4) void attn(
    const unsigned short* __restrict__ q, const unsigned short* __restrict__ Kf,
    const unsigned short* __restrict__ Vf, float* __restrict__ out) {
  __shared__ union {
    unsigned Pb[4][2][64][4];                            // 8 KB (main loop)
    struct { float A[32][68]; float B[32][68]; } Oc;     // 17.4 KB (combine)
  } sm;
  __shared__ float Lc[4][32];

  const int tid = threadIdx.x;
  const int lane = tid & 63;
  const int w = tid >> 6;
  const int u = lane & 15;
  const int qd = lane >> 4;

  const int bx = blockIdx.x;
  const int s4 = bx & 3;
  const int m = bx >> 2;
  const int b = m >> 5;
  const int u0 = m & 31;
  const int qt = (s4 & 1) ? (63 - u0) : u0;
  const int rh = s4 >> 1;
  const int g0 = qt * 64;
  const int r0 = rh * 32;  // row offset within tile

  const unsigned short* qp = q + (size_t)b * 4096 * 64;
  const unsigned short* kfp = Kf + (size_t)b * 64 * 4096;
  const unsigned short* vfp = Vf + (size_t)b * 64 * 4096;

  // Q B-frags (32 rows): qB[nb][kh]
  short8 qB[2][2];
#pragma unroll
  for (int nb = 0; nb < 2; ++nb)
#pragma unroll
    for (int kh = 0; kh < 2; ++kh)
      qB[nb][kh] = *reinterpret_cast<const short8*>(
          &qp[(size_t)(g0 + r0 + nb * 16 + u) * 64 + kh * 32 + qd * 8]);

  floatx4 OT[4][2];  // [mb][nb]: O^T[h=mb*16+qd*4+r][qr=nb*16+u]
#pragma unroll
  for (int mb = 0; mb < 4; ++mb)
#pragma unroll
    for (int nb = 0; nb < 2; ++nb) OT[mb][nb] = (floatx4)0.0f;
  float L[2] = {0.f, 0.f};

  const int ktmax = (qt < 16) ? 15 : qt;

  for (int kt = w; kt <= ktmax; kt += 4) {
    const unsigned short* kb = kfp + (size_t)kt * 4096;
    const unsigned short* vb = vfp + (size_t)kt * 4096;
    const bool diag = (qt >= 16) && (kt == qt);

#pragma unroll
    for (int sp = 0; sp < 2; ++sp) {
      short8 vA[4];  // frag f = sp*4+mb
#pragma unroll
      for (int mb = 0; mb < 4; ++mb)
        vA[mb] = *reinterpret_cast<const short8*>(
            &vb[(size_t)(sp * 4 + mb) * 512 + lane * 8]);

#pragma unroll
      for (int sbb = 0; sbb < 2; ++sbb) {
        short8 kA0 = *reinterpret_cast<const short8*>(
            &kb[(size_t)(0 * 4 + sp * 2 + sbb) * 512 + lane * 8]);
        short8 kA1 = *reinterpret_cast<const short8*>(
            &kb[(size_t)(1 * 4 + sp * 2 + sbb) * 512 + lane * 8]);

        floatx4 ST[2];  // [nb]: S^T[s=(sp*2+sbb)*16+qd*4+r][qr=nb*16+u]
#pragma unroll
        for (int nb = 0; nb < 2; ++nb) ST[nb] = (floatx4)0.0f;
#pragma unroll
        for (int nb = 0; nb < 2; ++nb) {
          ST[nb] = __builtin_amdgcn_mfma_f32_16x16x32_bf16(kA0, qB[nb][0], ST[nb], 0, 0, 0);
          ST[nb] = __builtin_amdgcn_mfma_f32_16x16x32_bf16(kA1, qB[nb][1], ST[nb], 0, 0, 0);
        }

        if (diag) {
#pragma unroll
          for (int nb = 0; nb < 2; ++nb)
#pragma unroll
            for (int r = 0; r < 4; ++r) {
              int sl = (sp * 2 + sbb) * 16 + qd * 4 + r;
              int qr = r0 + nb * 16 + u;
              if (sl > qr) ST[nb][r] = -__builtin_inff();
            }
        }

        // exp2 (logits already scaled), L partials, pack to B-frag dwords
#pragma unroll
        for (int nb = 0; nb < 2; ++nb) {
#pragma unroll
          for (int r = 0; r < 4; ++r)
            ST[nb][r] = __builtin_amdgcn_exp2f(ST[nb][r]);
          L[nb] += (ST[nb][0] + ST[nb][1]) + (ST[nb][2] + ST[nb][3]);
          unsigned lo = pkbf(ST[nb][0], ST[nb][1]);
          unsigned hi = pkbf(ST[nb][2], ST[nb][3]);
          int dl = (sbb * 2 + (qd >> 1)) * 16 + u;  // dest lane
          int d0 = (qd & 1) * 2;                    // dest dword pair
          *reinterpret_cast<uint2*>(&sm.Pb[w][nb][dl][d0]) = make_uint2(lo, hi);
        }
      }

      // PV: O^T += V^T P^T
#pragma unroll
      for (int nb = 0; nb < 2; ++nb) {
        short8 pB = *reinterpret_cast<const short8*>(&sm.Pb[w][nb][lane][0]);
#pragma unroll
        for (int mb = 0; mb < 4; ++mb)
          OT[mb][nb] = __builtin_amdgcn_mfma_f32_16x16x32_bf16(vA[mb], pB, OT[mb][nb], 0, 0, 0);
      }
    }
  }

  // ---- combine across the 4 kt-split waves ----
#pragma unroll
  for (int nb = 0; nb < 2; ++nb) {
    L[nb] += __shfl_xor(L[nb], 16);
    L[nb] += __shfl_xor(L[nb], 32);
  }
  if (lane < 16) {
#pragma unroll
    for (int nb = 0; nb < 2; ++nb) Lc[w][nb * 16 + lane] = L[nb];
  }
  __syncthreads();  // all Pb usage complete (LDS overlay)

  if (w == 1) {
#pragma unroll
    for (int mb = 0; mb < 4; ++mb)
#pragma unroll
      for (int nb = 0; nb < 2; ++nb)
        *reinterpret_cast<floatx4*>(&sm.Oc.A[nb * 16 + u][mb * 16 + qd * 4]) = OT[mb][nb];
  }
  if (w == 3) {
#pragma unroll
    for (int mb = 0; mb < 4; ++mb)
#pragma unroll
      for (int nb = 0; nb < 2; ++nb)
        *reinterpret_cast<floatx4*>(&sm.Oc.B[nb * 16 + u][mb * 16 + qd * 4]) = OT[mb][nb];
  }
  __syncthreads();
  if (w == 0) {
#pragma unroll
    for (int mb = 0; mb < 4; ++mb)
#pragma unroll
      for (int nb = 0; nb < 2; ++nb)
        OT[mb][nb] += *reinterpret_cast<const floatx4*>(&sm.Oc.A[nb * 16 + u][mb * 16 + qd * 4]);
  }
  if (w == 2) {
#pragma unroll
    for (int mb = 0; mb < 4; ++mb)
#pragma unroll
      for (int nb = 0; nb < 2; ++nb) {
        OT[mb][nb] += *reinterpret_cast<const floatx4*>(&sm.Oc.B[nb * 16 + u][mb * 16 + qd * 4]);
        *reinterpret_cast<floatx4*>(&sm.Oc.B[nb * 16 + u][mb * 16 + qd * 4]) = OT[mb][nb];
      }
  }
  __syncthreads();
  if (w == 0) {
#pragma unroll
    for (int mb = 0; mb < 4; ++mb)
#pragma unroll
      for (int nb = 0; nb < 2; ++nb) {
        OT[mb][nb] += *reinterpret_cast<const floatx4*>(&sm.Oc.B[nb * 16 + u][mb * 16 + qd * 4]);
        *reinterpret_cast<floatx4*>(&sm.Oc.A[nb * 16 + u][mb * 16 + qd * 4]) = OT[mb][nb];
      }
  }
  __syncthreads();

  // cooperative normalize + coalesced store (32 rows x 64 cols)
  {
    int qr = tid >> 3;            // 0..31
    int h0 = (tid & 7) * 8;       // 0..56
    float Ltot = (Lc[0][qr] + Lc[1][qr]) + (Lc[2][qr] + Lc[3][qr]);
    float inv = 1.0f / Ltot;
    float* op = out + ((size_t)b * 4096 + g0 + r0 + qr) * 64 + h0;
    floatx4 v0 = *reinterpret_cast<const floatx4*>(&sm.Oc.A[qr][h0]);
    floatx4 v1 = *reinterpret_cast<const floatx4*>(&sm.Oc.A[qr][h0 + 4]);
    v0 *= inv;
    v1 *= inv;
    *reinterpret_cast<floatx4*>(&op[0]) = v0;
    *reinterpret_cast<floatx4*>(&op[4]) = v1;
  }
}

// ---------------------------------------------------------------------------
extern "C" void kernel_launch(void* const* d_in, const int* in_sizes, int n_in,
                              void* d_out, int out_size, void* d_ws, size_t ws_size,
                              hipStream_t stream) {
  const float* x  = (const float*)d_in[0];  // [8][4096][512] fp32
  const float* Wq = (const float*)d_in[1];  // [512][64] fp32
  const float* Wk = (const float*)d_in[2];
  const float* Wv = (const float*)d_in[3];

  unsigned short* ws = (unsigned short*)d_ws;
  unsigned short* Wtf = ws;                  // 98304 shorts (frag-linear weights)
  unsigned short* qb = ws + 131072;          // 32768*64 bf16 row-major (pre-scaled)
  unsigned short* kf = qb + 2097152;         // frag-linear K tiles
  unsigned short* vf = kf + 2097152;         // frag-linear V^T tiles

  wtrans<<<384, 256, 0, stream>>>(Wq, Wk, Wv, Wtf);
  proj<<<1024, 256, 0, stream>>>(x, Wtf, qb, kf, vf);
  attn<<<1024, 256, 0, stream>>>(qb, kf, vf, (float*)d_out);
}